// Round 9
// baseline (157.376 us; speedup 1.0000x reference)
//
#include <hip/hip_runtime.h>
#include <stddef.h>

// DeepProbLog addition reasoner, round 8 kernel (resubmit — round-8 bench
// failed on GPU acquisition, never ran). SIMPLEST correct form.
//   out[b,k] = sum_{i+j==k} p1[b,i]*p2[b,j], normalized by (row-sum + 1e-9)
// B = 1048576.
//
// Rounds 6/7: the LDS-pipelined kernel has a deterministic bug (identical
// absmax across two different builds) that inspection failed to find twice.
// Pivot: per-lane direct kernel — no LDS, no fences, no barriers. Round-2
// counters showed FETCH ~41MB < 84MB inputs => inputs are L3-resident after
// the harness's restore copy; read coalescing is near-irrelevant, the floor
// is write-dominated (~80MB -> ~13-20us). Per-lane rows: 5x float2 loads
// (rows 8B-aligned), 100 FMAs, exact divide (matches the round-1/2 math that
// passed at absmax 4.9e-4), 19 scalar dword stores. Full occupancy, pure TLP.

#define EPS 1e-9f

constexpr int THREADS = 256;

__global__ __launch_bounds__(THREADS)
void dpl_add_kernel(const float* __restrict__ p1,
                    const float* __restrict__ p2,
                    float* __restrict__ out,
                    int B) {
    const int b = blockIdx.x * THREADS + threadIdx.x;
    if (b >= B) return;

    // ---- load own row: 10 floats = 5 x float2 (row byte offset b*40, 8B-aligned) ----
    const float2* r1 = reinterpret_cast<const float2*>(p1 + (size_t)b * 10);
    const float2* r2 = reinterpret_cast<const float2*>(p2 + (size_t)b * 10);
    float a[10], c[10];
    #pragma unroll
    for (int i = 0; i < 5; ++i) {
        float2 va = r1[i];
        float2 vc = r2[i];
        a[2 * i] = va.x; a[2 * i + 1] = va.y;
        c[2 * i] = vc.x; c[2 * i + 1] = vc.y;
    }

    // ---- binned outer product: s[i+j] += a[i]*c[j] (lexicographic ij) ----
    float s[19];
    #pragma unroll
    for (int k = 0; k < 19; ++k) s[k] = 0.0f;
    #pragma unroll
    for (int i = 0; i < 10; ++i) {
        #pragma unroll
        for (int j = 0; j < 10; ++j) {
            s[i + j] = fmaf(a[i], c[j], s[i + j]);
        }
    }

    // ---- normalize (exact divide: bit-matches the round-1/2 passing math) ----
    float tot = 0.0f;
    #pragma unroll
    for (int k = 0; k < 19; ++k) tot += s[k];
    const float den = tot + EPS;

    // ---- store 19 floats (scalar dwords; every byte written once) ----
    float* o = out + (size_t)b * 19;
    #pragma unroll
    for (int k = 0; k < 19; ++k) o[k] = s[k] / den;
}

extern "C" void kernel_launch(void* const* d_in, const int* in_sizes, int n_in,
                              void* d_out, int out_size, void* d_ws, size_t ws_size,
                              hipStream_t stream) {
    const float* p1 = (const float*)d_in[0];
    const float* p2 = (const float*)d_in[1];
    float* out = (float*)d_out;
    const int B = in_sizes[0] / 10;   // p1 is [B,10]

    const int grid = (B + THREADS - 1) / THREADS;   // 4096 for B=1048576
    dpl_add_kernel<<<grid, THREADS, 0, stream>>>(p1, p2, out, B);
}